// Round 1
// baseline (40.721 us; speedup 1.0000x reference)
//
#include <hip/hip_runtime.h>

// BilateralFilter: N=8 images [N,1,512,512] depth/mask, [N,3,512,512] color.
// 3x3 window, sigma=0.8 for both density (depth) and color terms.
// One thread per pixel; all 3 channels per thread; single-pass accumulation.

constexpr int HH = 512;
constexpr int WW = 512;
constexpr int HW = HH * WW;

// K = -(1/(2*0.8^2)) * log2(e) = -0.78125 * 1.4426950408889634
#define KEXP (-1.1271055f)

__global__ __launch_bounds__(256) void bilateral_kernel(
    const float* __restrict__ depth,   // [N,1,H,W]
    const float* __restrict__ color,   // [N,3,H,W]
    const float* __restrict__ mask,    // [N,1,H,W]
    float* __restrict__ out)           // [N,3,H,W]
{
    int idx = blockIdx.x * 256 + threadIdx.x;
    int w = idx & (WW - 1);
    int h = (idx >> 9) & (HH - 1);
    int n = idx >> 18;          // 0..7

    // Normalized spatial gaussian, indexed by di^2+dj^2 (0,1,2):
    // e1=exp(-0.78125), e2=e1^2, sum = 1+4*e1+4*e2 = 3.669768
    const float WS0 = 0.2724967f;
    const float WS1 = 0.1247577f;
    const float WS2 = 0.0571180f;

    const float* dptr = depth + (size_t)n * HW;
    const float* mptr = mask  + (size_t)n * HW;
    const float* cptr = color + (size_t)n * 3 * HW;

    const int base = h * WW + w;
    const float dc = dptr[base];
    const float c0 = cptr[base];
    const float c1 = cptr[base + HW];
    const float c2 = cptr[base + 2 * HW];

    float Swd = 0.f, Swc = 0.f, St = 0.f;
    float Stc0 = 0.f, Stc1 = 0.f, Stc2 = 0.f;
    float Sc0 = 0.f, Sc1 = 0.f, Sc2 = 0.f;

    #pragma unroll
    for (int di = -1; di <= 1; ++di) {
        const int hh = h + di;
        const bool rowv = ((unsigned)hh < (unsigned)HH);
        #pragma unroll
        for (int dj = -1; dj <= 1; ++dj) {
            const int ww = w + dj;
            const bool v = rowv && ((unsigned)ww < (unsigned)WW);
            const int off = hh * WW + ww;

            const float dp  = v ? dptr[off] : 0.0f;
            const float mp  = v ? mptr[off] : 0.0f;
            const float cp0 = v ? cptr[off] : 0.0f;
            const float cp1 = v ? cptr[off + HW] : 0.0f;
            const float cp2 = v ? cptr[off + 2 * HW] : 0.0f;

            const float dd = dp - dc;
            const float wd = __builtin_amdgcn_exp2f(KEXP * dd * dd);

            const float e0 = cp0 - c0;
            const float e1 = cp1 - c1;
            const float e2 = cp2 - c2;
            const float wc = __builtin_amdgcn_exp2f(KEXP * e0 * e0)
                           + __builtin_amdgcn_exp2f(KEXP * e1 * e1)
                           + __builtin_amdgcn_exp2f(KEXP * e2 * e2);

            const int d2 = di * di + dj * dj;
            const float ws = (d2 == 0) ? WS0 : ((d2 == 1) ? WS1 : WS2);

            const float t = wd * wc * ws * mp;

            Swd += wd;
            Swc += wc;
            St  += t;
            Stc0 += t * cp0;
            Stc1 += t * cp1;
            Stc2 += t * cp2;
            Sc0 += cp0;
            Sc1 += cp1;
            Sc2 += cp2;
        }
    }

    const float inv_norm = 1.0f / (Swd * Swc);
    const float sum_w = St * inv_norm + 9e-7f;
    const float inv_sw = 1.0f / sum_w;

    out[(size_t)n * 3 * HW + base]          = (Stc0 * inv_norm + 1e-7f * Sc0) * inv_sw;
    out[(size_t)n * 3 * HW + HW + base]     = (Stc1 * inv_norm + 1e-7f * Sc1) * inv_sw;
    out[(size_t)n * 3 * HW + 2 * HW + base] = (Stc2 * inv_norm + 1e-7f * Sc2) * inv_sw;
}

extern "C" void kernel_launch(void* const* d_in, const int* in_sizes, int n_in,
                              void* d_out, int out_size, void* d_ws, size_t ws_size,
                              hipStream_t stream) {
    const float* depth = (const float*)d_in[0];
    const float* color = (const float*)d_in[1];
    const float* mask  = (const float*)d_in[2];
    float* out = (float*)d_out;

    const int total = 8 * HW;           // 2,097,152 pixels
    const int blocks = total / 256;     // 8192
    bilateral_kernel<<<blocks, 256, 0, stream>>>(depth, color, mask, out);
}

// Round 2
// 33.152 us; speedup vs baseline: 1.2283x; 1.2283x over previous
//
#include <hip/hip_runtime.h>

// BilateralFilter: N=8 images, [N,1,512,512] depth/mask, [N,3,512,512] color, fp32.
// 3x3 window, sigma=0.8 (density + color). 4 pixels per thread along w:
// aligned float4 loads + 2 predicated edge scalars per row-plane,
// wave-uniform row-validity branches, float4 stores.

constexpr int HH = 512;
constexpr int WW = 512;
constexpr int HW = HH * WW;

// K = -(1/(2*0.8^2)) * log2(e)
#define KEXP (-1.1271055f)
#define E2(x) __builtin_amdgcn_exp2f(x)

__global__ __launch_bounds__(256) void bilateral4(
    const float* __restrict__ depth,   // [N,1,H,W]
    const float* __restrict__ color,   // [N,3,H,W]
    const float* __restrict__ mask,    // [N,1,H,W]
    float* __restrict__ out)           // [N,3,H,W]
{
    const int idx = blockIdx.x * 256 + threadIdx.x;
    const int w0 = (idx & 127) << 2;        // 0..508, step 4
    const int h  = (idx >> 7) & (HH - 1);
    const int n  = idx >> 16;               // 0..7

    // Normalized spatial gaussian by d2 = di^2+dj^2 (0,1,2)
    const float WS0 = 0.2724967f;
    const float WS1 = 0.1247577f;
    const float WS2 = 0.0571180f;

    const float* dptr = depth + (size_t)n * HW;
    const float* mptr = mask  + (size_t)n * HW;
    const float* cptr = color + (size_t)n * 3 * HW;

    const bool hasL = (w0 > 0);
    const bool hasR = (w0 < WW - 4);

    // 6-wide windows (w0-1 .. w0+4) for 3 rows x 5 planes
    float Dw[3][6], Mw[3][6], C0w[3][6], C1w[3][6], C2w[3][6];

    #pragma unroll
    for (int r = 0; r < 3; ++r) {
        const int hh = h + r - 1;
        const bool rowv = ((unsigned)hh < (unsigned)HH);  // wave-uniform
        const int ro = hh * WW + w0;
        #define LOAD6(dst, base) do {                                          \
            if (rowv) {                                                        \
                const float4 m4 = *reinterpret_cast<const float4*>((base) + ro); \
                dst[r][1] = m4.x; dst[r][2] = m4.y;                            \
                dst[r][3] = m4.z; dst[r][4] = m4.w;                            \
                dst[r][0] = hasL ? (base)[ro - 1] : 0.0f;                      \
                dst[r][5] = hasR ? (base)[ro + 4] : 0.0f;                      \
            } else {                                                           \
                dst[r][0] = 0.f; dst[r][1] = 0.f; dst[r][2] = 0.f;             \
                dst[r][3] = 0.f; dst[r][4] = 0.f; dst[r][5] = 0.f;             \
            }                                                                  \
        } while (0)
        LOAD6(Dw,  dptr);
        LOAD6(Mw,  mptr);
        LOAD6(C0w, cptr);
        LOAD6(C1w, cptr + HW);
        LOAD6(C2w, cptr + 2 * HW);
        #undef LOAD6
    }

    float Swd[4], Swc[4], St[4];
    float Stc0[4], Stc1[4], Stc2[4];
    float Sc0[4], Sc1[4], Sc2[4];
    #pragma unroll
    for (int i = 0; i < 4; ++i) {
        Swd[i] = 0.f; Swc[i] = 0.f; St[i] = 0.f;
        Stc0[i] = 0.f; Stc1[i] = 0.f; Stc2[i] = 0.f;
        Sc0[i] = 0.f; Sc1[i] = 0.f; Sc2[i] = 0.f;
    }

    #pragma unroll
    for (int r = 0; r < 3; ++r) {
        const float wsMid  = (r == 1) ? WS0 : WS1;  // dj == 0
        const float wsSide = (r == 1) ? WS1 : WS2;  // dj == +-1
        #pragma unroll
        for (int i = 0; i < 4; ++i) {
            const float dc  = Dw[1][i + 1];
            const float cc0 = C0w[1][i + 1];
            const float cc1 = C1w[1][i + 1];
            const float cc2 = C2w[1][i + 1];
            #pragma unroll
            for (int dj = 0; dj < 3; ++dj) {
                const int c = i + dj;           // window col 0..5
                const float dp = Dw[r][c];
                const float mp = Mw[r][c];
                const float p0 = C0w[r][c];
                const float p1 = C1w[r][c];
                const float p2 = C2w[r][c];

                const float dd = dp - dc;
                const float wd = E2(KEXP * dd * dd);

                const float f0 = p0 - cc0;
                const float f1 = p1 - cc1;
                const float f2 = p2 - cc2;
                const float wc = E2(KEXP * f0 * f0)
                               + E2(KEXP * f1 * f1)
                               + E2(KEXP * f2 * f2);

                const float ws = (dj == 1) ? wsMid : wsSide;
                const float t = wd * wc * ws * mp;

                Swd[i] += wd;
                Swc[i] += wc;
                St[i]  += t;
                Stc0[i] += t * p0;
                Stc1[i] += t * p1;
                Stc2[i] += t * p2;
                Sc0[i] += p0;
                Sc1[i] += p1;
                Sc2[i] += p2;
            }
        }
    }

    float r0[4], r1[4], r2[4];
    #pragma unroll
    for (int i = 0; i < 4; ++i) {
        const float inv_norm = 1.0f / (Swd[i] * Swc[i]);
        const float sum_w = St[i] * inv_norm + 9e-7f;
        const float inv_sw = 1.0f / sum_w;
        r0[i] = (Stc0[i] * inv_norm + 1e-7f * Sc0[i]) * inv_sw;
        r1[i] = (Stc1[i] * inv_norm + 1e-7f * Sc1[i]) * inv_sw;
        r2[i] = (Stc2[i] * inv_norm + 1e-7f * Sc2[i]) * inv_sw;
    }

    float* po = out + (size_t)n * 3 * HW + h * WW + w0;
    *reinterpret_cast<float4*>(po)          = make_float4(r0[0], r0[1], r0[2], r0[3]);
    *reinterpret_cast<float4*>(po + HW)     = make_float4(r1[0], r1[1], r1[2], r1[3]);
    *reinterpret_cast<float4*>(po + 2 * HW) = make_float4(r2[0], r2[1], r2[2], r2[3]);
}

extern "C" void kernel_launch(void* const* d_in, const int* in_sizes, int n_in,
                              void* d_out, int out_size, void* d_ws, size_t ws_size,
                              hipStream_t stream) {
    const float* depth = (const float*)d_in[0];
    const float* color = (const float*)d_in[1];
    const float* mask  = (const float*)d_in[2];
    float* out = (float*)d_out;

    const int total_threads = 8 * HH * (WW / 4);   // 524288
    const int blocks = total_threads / 256;        // 2048
    bilateral4<<<blocks, 256, 0, stream>>>(depth, color, mask, out);
}